// Round 10
// baseline (226.143 us; speedup 1.0000x reference)
//
#include <hip/hip_runtime.h>

#define RS2f 0.70710678118654752f

// DPP quad_perm encodings: sel0 | sel1<<2 | sel2<<4 | sel3<<6
#define QP_XOR1 0xB1   // [1,0,3,2]
#define QP_XOR2 0x4E   // [2,3,0,1]
#define QP_BC0  0x00
#define QP_BC1  0x55
#define QP_BC2  0xAA
#define QP_BC3  0xFF

typedef float v2f __attribute__((ext_vector_type(2)));
typedef float v4f __attribute__((ext_vector_type(4)));
typedef v4f v4fu __attribute__((aligned(4)));   // 4B-aligned vector load

template<int CTRL> __device__ __forceinline__ float dppf(float x) {
  return __int_as_float(__builtin_amdgcn_update_dpp(
      0, __float_as_int(x), CTRL, 0xF, 0xF, true));
}
template<int CTRL> __device__ __forceinline__ v2f dpp2(v2f v) {
  v2f r; r.x = dppf<CTRL>(v.x); r.y = dppf<CTRL>(v.y); return r;
}

__device__ __forceinline__ float sxor(float x, int sm) {
  return __int_as_float(__float_as_int(x) ^ sm);
}
__device__ __forceinline__ v2f vlo(v4f v) { return __builtin_shufflevector(v, v, 0, 1); }
__device__ __forceinline__ v2f vhi(v4f v) { return __builtin_shufflevector(v, v, 2, 3); }
__device__ __forceinline__ v4f loadu4(const float* p) { return *(const v4fu*)p; }

// ---- packed-fp32 helpers: complex / packed arithmetic in single VOP3P ops --
// perp(x) = (-x.y, x.x) = i*x ; perc(x) = (x.y, -x.x) = -i*x

// plain packed: d = a*b + c
__device__ __forceinline__ v2f pk_fma2(v2f a, v2f b, v2f c) {
  v2f d;
  asm("v_pk_fma_f32 %0, %1, %2, %3 op_sel:[0,0,0] op_sel_hi:[1,1,1]"
      : "=v"(d) : "v"(a), "v"(b), "v"(c));
  return d;
}
// plain packed: d = a*b
__device__ __forceinline__ v2f pk_mul2(v2f a, v2f b) {
  v2f d;
  asm("v_pk_mul_f32 %0, %1, %2 op_sel:[0,0] op_sel_hi:[1,1]"
      : "=v"(d) : "v"(a), "v"(b));
  return d;
}
// plain packed: d = a + b
__device__ __forceinline__ v2f pk_add2(v2f a, v2f b) {
  v2f d;
  asm("v_pk_add_f32 %0, %1, %2 op_sel:[0,0] op_sel_hi:[1,1]"
      : "=v"(d) : "v"(a), "v"(b));
  return d;
}
// d = c.lo * x + acc
__device__ __forceinline__ v2f pk_fma_rlo(v2f c, v2f x, v2f acc) {
  v2f d;
  asm("v_pk_fma_f32 %0, %1, %2, %3 op_sel:[0,0,0] op_sel_hi:[0,1,1]"
      : "=v"(d) : "v"(c), "v"(x), "v"(acc));
  return d;
}
// d = -c.lo * x + acc
__device__ __forceinline__ v2f pk_fma_nrlo(v2f c, v2f x, v2f acc) {
  v2f d;
  asm("v_pk_fma_f32 %0, %1, %2, %3 op_sel:[0,0,0] op_sel_hi:[0,1,1] neg_lo:[1,0,0] neg_hi:[1,0,0]"
      : "=v"(d) : "v"(c), "v"(x), "v"(acc));
  return d;
}
// d = c.hi * x + acc
__device__ __forceinline__ v2f pk_fma_rhi(v2f c, v2f x, v2f acc) {
  v2f d;
  asm("v_pk_fma_f32 %0, %1, %2, %3 op_sel:[1,0,0] op_sel_hi:[1,1,1]"
      : "=v"(d) : "v"(c), "v"(x), "v"(acc));
  return d;
}
// d = -c.hi * x + acc
__device__ __forceinline__ v2f pk_fma_nrhi(v2f c, v2f x, v2f acc) {
  v2f d;
  asm("v_pk_fma_f32 %0, %1, %2, %3 op_sel:[1,0,0] op_sel_hi:[1,1,1] neg_lo:[1,0,0] neg_hi:[1,0,0]"
      : "=v"(d) : "v"(c), "v"(x), "v"(acc));
  return d;
}
// d = c.hi * perp(x) + acc
__device__ __forceinline__ v2f pk_fma_rhip(v2f c, v2f x, v2f acc) {
  v2f d;
  asm("v_pk_fma_f32 %0, %1, %2, %3 op_sel:[1,1,0] op_sel_hi:[1,0,1] neg_lo:[0,1,0]"
      : "=v"(d) : "v"(c), "v"(x), "v"(acc));
  return d;
}
// d = c.hi * perc(x) + acc
__device__ __forceinline__ v2f pk_fma_rhic(v2f c, v2f x, v2f acc) {
  v2f d;
  asm("v_pk_fma_f32 %0, %1, %2, %3 op_sel:[1,1,0] op_sel_hi:[1,0,1] neg_hi:[0,1,0]"
      : "=v"(d) : "v"(c), "v"(x), "v"(acc));
  return d;
}
// d = c.hi * perp(x)
__device__ __forceinline__ v2f pk_mul_rhip(v2f c, v2f x) {
  v2f d;
  asm("v_pk_mul_f32 %0, %1, %2 op_sel:[1,1] op_sel_hi:[1,0] neg_lo:[0,1]"
      : "=v"(d) : "v"(c), "v"(x));
  return d;
}
// d = c.hi * x
__device__ __forceinline__ v2f pk_mul_rhi(v2f c, v2f x) {
  v2f d;
  asm("v_pk_mul_f32 %0, %1, %2 op_sel:[1,0] op_sel_hi:[1,1]"
      : "=v"(d) : "v"(c), "v"(x));
  return d;
}
// d = -c.hi * x
__device__ __forceinline__ v2f pk_mul_nrhi(v2f c, v2f x) {
  v2f d;
  asm("v_pk_mul_f32 %0, %1, %2 op_sel:[1,0] op_sel_hi:[1,1] neg_lo:[1,0] neg_hi:[1,0]"
      : "=v"(d) : "v"(c), "v"(x));
  return d;
}
// d = c.lo * x
__device__ __forceinline__ v2f pk_mul_rlo(v2f c, v2f x) {
  v2f d;
  asm("v_pk_mul_f32 %0, %1, %2 op_sel:[0,0] op_sel_hi:[0,1]"
      : "=v"(d) : "v"(c), "v"(x));
  return d;
}

// native half-angle sincos: s = sin(x/2), c = cos(x/2)
__device__ __forceinline__ void hsc(float x, float* s, float* c) {
  float t = x * 0.07957747154594767f;   // 0.5 / (2*pi), input in revolutions
  *s = __builtin_amdgcn_sinf(t);
  *c = __builtin_amdgcn_cosf(t);
}

// Closed-form row0 of U = RZ(a4)RY(a3)RZ(a2)RY(a1)RZ(a0)·H  (verified r8).
__device__ __forceinline__ void build_gate(float a0, float a1, float a2, float a3, float a4,
                                           v2f &WA, v2f &WB) {
  float sBp, cBp, sBm, cBm, sC, cC, sP, cP, sM, cM;
  hsc(a1 + a3, &sBp, &cBp);
  hsc(a1 - a3, &sBm, &cBm);
  hsc(a2,      &sC,  &cC);
  hsc(a0 + a4, &sP,  &cP);
  hsc(a0 - a4, &sM,  &cM);
  float m00r =  cBp * cC, m00i = -cBm * sC;
  float m01r = -sBp * cC, m01i =  sBm * sC;
  float alr = fmaf(m00r, cP,  m00i * sP);
  float ali = fmaf(m00i, cP, -m00r * sP);
  float ber = fmaf(m01r, cM, -m01i * sM);
  float bei = fmaf(m01i, cM,  m01r * sM);
  WA.x = RS2f * (alr + ber); WA.y = RS2f * (ali + bei);
  WB.x = RS2f * (alr - ber); WB.y = RS2f * (ali - bei);
}

// ---- per-lane direct angle selects (verified r4) ----
#define SEL_MAIN                                                             \
  a0 = l3 ? Ac.w : Ac.x;                                                     \
  a1 = l3 ? 0.f  : Ac.y;                                                     \
  a2 = l2 ? Bc.x : (l3 ? 0.f : Ac.z);                                        \
  a3 = l0 ? Ac.w : (l1 ? Bc.x : (l2 ? Bc.y : 0.f));                          \
  a4 = l0 ? Bc.x : (l1 ? Bc.y : (l2 ? Bc.z : 0.f));

#define SEL_TAIL                                                             \
  a0 = l0 ? Ac.x : (l1 ? Ac.y : 0.f);                                        \
  a1 = l0 ? Ac.y : (l1 ? Ac.z : 0.f);                                        \
  a2 = l0 ? Ac.z : (l1 ? Ac.w : 0.f);                                        \
  a3 = l0 ? Ac.w : 0.f;                                                      \
  a4 = l0 ? Bc.x : 0.f;

// Apply gate (WcA/WcB packed pairs) + CRZ + Ry + Z expectations.
// r5-verified math: serial 4-deep pk chains, merged intra-lane Ry⊗Ry.
#define APPLY_Z do {                                                         \
  { v2f UA = dpp2<QP_BC0>(WcA), UB = dpp2<QP_BC0>(WcB);                      \
    UA.x = sxor(UA.x, sm0); UB.y = sxor(UB.y, sm0);                          \
    _Pragma("unroll")                                                        \
    for (int k = 0; k < 4; ++k) {                                            \
      v2f p = dpp2<QP_XOR2>(s[k]);                                           \
      v2f a = s[k];                                                          \
      s[k] = pk_fma_rlo(UA, a, pk_fma_rhip(UA, a,                            \
               pk_fma_rlo(UB, p, pk_mul_rhip(UB, p))));                      \
    } }                                                                      \
  { v2f UA = dpp2<QP_BC1>(WcA), UB = dpp2<QP_BC1>(WcB);                      \
    UA.x = sxor(UA.x, sm1); UB.y = sxor(UB.y, sm1);                          \
    _Pragma("unroll")                                                        \
    for (int k = 0; k < 4; ++k) {                                            \
      v2f p = dpp2<QP_XOR1>(s[k]);                                           \
      v2f a = s[k];                                                          \
      s[k] = pk_fma_rlo(UA, a, pk_fma_rhip(UA, a,                            \
               pk_fma_rlo(UB, p, pk_mul_rhip(UB, p))));                      \
    } }                                                                      \
  { v2f W0 = dpp2<QP_BC2>(WcA), W1 = dpp2<QP_BC2>(WcB);                      \
    _Pragma("unroll")                                                        \
    for (int k = 0; k < 2; ++k) {                                            \
      v2f lo = s[k], hi = s[k+2];                                            \
      s[k]   = pk_fma_rlo(W0, lo, pk_fma_rhip(W0, lo,                        \
                 pk_fma_rlo(W1, hi, pk_mul_rhip(W1, hi))));                  \
      s[k+2] = pk_fma_rlo(W1, lo, pk_fma_rhic(W1, lo,                        \
                 pk_fma_nrlo(W0, hi, pk_mul_rhip(W0, hi))));                 \
    } }                                                                      \
  { v2f W0 = dpp2<QP_BC3>(WcA), W1 = dpp2<QP_BC3>(WcB);                      \
    _Pragma("unroll")                                                        \
    for (int k = 0; k < 4; k += 2) {                                         \
      v2f lo = s[k], hi = s[k+1];                                            \
      s[k]   = pk_fma_rlo(W0, lo, pk_fma_rhip(W0, lo,                        \
                 pk_fma_rlo(W1, hi, pk_mul_rhip(W1, hi))));                  \
      s[k+1] = pk_fma_rlo(W1, lo, pk_fma_rhic(W1, lo,                        \
                 pk_fma_nrlo(W0, hi, pk_mul_rhip(W0, hi))));                 \
    } }                                                                      \
  _Pragma("unroll")                                                          \
  for (int k = 0; k < 4; ++k)                                                \
    s[k] = pk_fma_rlo(czv[k], s[k], pk_mul_rhip(czv[k], s[k]));              \
  _Pragma("unroll")                                                          \
  for (int k = 0; k < 4; ++k) {                                              \
    v2f p = dpp2<QP_XOR2>(s[k]);                                             \
    s[k] = pk_fma_rlo(RY0, s[k], pk_mul_rhi(RY0, p));                        \
  }                                                                          \
  _Pragma("unroll")                                                          \
  for (int k = 0; k < 4; ++k) {                                              \
    v2f p = dpp2<QP_XOR1>(s[k]);                                             \
    s[k] = pk_fma_rlo(RY1, s[k], pk_mul_rhi(RY1, p));                        \
  }                                                                          \
  { /* merged intra-lane Ry⊗Ry (r5-verified) */                              \
    v2f t0 = s[0], t1 = s[1], t2 = s[2], t3 = s[3];                          \
    s[0] = pk_fma_rlo(C2CS, t0, pk_fma_nrhi(C2CS, t1,                        \
             pk_fma_nrhi(C2CS, t2, pk_mul_rlo(S2CS, t3))));                  \
    s[1] = pk_fma_rhi(C2CS, t0, pk_fma_rlo(C2CS, t1,                         \
             pk_fma_nrlo(S2CS, t2, pk_mul_nrhi(C2CS, t3))));                 \
    s[2] = pk_fma_rhi(C2CS, t0, pk_fma_nrlo(S2CS, t1,                        \
             pk_fma_rlo(C2CS, t2, pk_mul_nrhi(C2CS, t3))));                  \
    s[3] = pk_fma_rlo(S2CS, t0, pk_fma_rhi(C2CS, t1,                         \
             pk_fma_rhi(C2CS, t2, pk_mul_rlo(C2CS, t3))));                   \
  }                                                                          \
  { v2f q0 = pk_mul2(s[0], s[0]), q1 = pk_mul2(s[1], s[1]);                  \
    v2f q2 = pk_mul2(s[2], s[2]), q3 = pk_mul2(s[3], s[3]);                  \
    float p0 = q0.x + q0.y, p1 = q1.x + q1.y;                                \
    float p2 = q2.x + q2.y, p3 = q3.x + q3.y;                                \
    float s01 = p0 + p1, s23 = p2 + p3;                                      \
    float t_  = s01 + s23;                                                   \
    npA.x = sxor(t_, sm0);                                                   \
    npA.y = sxor(t_, sm1);                                                   \
    npB.x = s01 - s23;                                                       \
    npB.y = (p0 - p1) + (p2 - p3);                                           \
  }                                                                          \
} while (0)

// LDS weight reads for the PENDING window — issued early (top of body).
#define BF_LOAD                                                              \
  const float* wp = swl + pdWin * 4;                                         \
  v4f wv0 = *(const v4f*)(wp);                                               \
  v4f wv1 = *(const v4f*)(wp + 784);                                         \
  v4f wv2 = *(const v4f*)(wp + 1568);                                        \
  v4f wv3 = *(const v4f*)(wp + 2352);                                        \
  v4f wv4 = *(const v4f*)(wp + 3136);

// Packed butterfly + packed fc1 fold — all through explicit pk asm.
#define BF_USE do {                                                          \
  v2f oA = pdA, oB = pdB;                                                    \
  oA = pk_add2(oA, dpp2<QP_XOR1>(oA)); oA = pk_add2(oA, dpp2<QP_XOR2>(oA));  \
  oB = pk_add2(oB, dpp2<QP_XOR1>(oB)); oB = pk_add2(oB, dpp2<QP_XOR2>(oB));  \
  h1v[0] = pk_fma2(vlo(wv0), oA, pk_fma2(vhi(wv0), oB, h1v[0]));             \
  h1v[1] = pk_fma2(vlo(wv1), oA, pk_fma2(vhi(wv1), oB, h1v[1]));             \
  h1v[2] = pk_fma2(vlo(wv2), oA, pk_fma2(vhi(wv2), oB, h1v[2]));             \
  h1v[3] = pk_fma2(vlo(wv3), oA, pk_fma2(vhi(wv3), oB, h1v[3]));             \
  h1v[4] = pk_fma2(vlo(wv4), oA, pk_fma2(vhi(wv4), oB, h1v[4]));             \
} while (0)

#define BF_FOLD do { BF_LOAD; BF_USE; } while (0)

#define SHIFT_PEND(WIN)  pdA = npA; pdB = npB; pdWin = (WIN);
#define ROTATE_W  WcA = WnA; WcB = WnB;

__global__ void __launch_bounds__(256)
quanv_kernel(const float* __restrict__ x,
             const float* __restrict__ crz_t,
             const float* __restrict__ ry_t,
             const float* __restrict__ fc1_w,
             const float* __restrict__ fc1_b,
             const float* __restrict__ fc2_w,
             const float* __restrict__ fc2_b,
             float* __restrict__ out, int B)
{
  __shared__ float sw[20 * 784];
  const int tid = threadIdx.x;
  for (int i = tid; i < (20 * 784) / 4; i += 256)
    ((float4*)sw)[i] = ((const float4*)fc1_w)[i];
  __syncthreads();

  const int l = tid & 3;                       // lane within 4-lane group
  const int b = (blockIdx.x * 256 + tid) >> 2; // element id
  if (b >= B) return;
  const float* img = x + (size_t)b * 784;
  const bool l0 = (l == 0), l1 = (l == 1), l2 = (l == 2), l3 = (l == 3);

  // per-lane load offsets (floats) for the direct-select scheme
  const int offA = l3 ? 84 : l * 29;                 // row i+l, col +l (l3: row i+3, col +0)
  const int offB = (l >= 2) ? 84 : (l + 1) * 28;     // row i+min(l+1,3), col +0

  // ---- uniform scalar-derived constants ----
  const float theta = crz_t[0];
  const float ryt   = ry_t[0];
  float cry, sry;
  hsc(ryt, &sry, &cry);
  const float sgn0 = (l & 2) ? sry : -sry;
  const float sgn1 = (l & 1) ? sry : -sry;
  const int sm0 = (l & 2) ? (int)0x80000000 : 0;
  const int sm1 = (l & 1) ? (int)0x80000000 : 0;

  v2f RY0, RY1, C2CS, S2CS;
  RY0.x = cry; RY0.y = sgn0;
  RY1.x = cry; RY1.y = sgn1;
  C2CS.x = cry * cry; C2CS.y = cry * sry;   // (c^2, c*s)
  S2CS.x = sry * sry; S2CS.y = cry * sry;   // (s^2, c*s)

  float g0,g1,g2,g3;
  if      (l == 0) { g0= 0.f; g1=-1.f; g2=-1.f; g3=0.f; }
  else if (l == 1) { g0=-1.f; g1=-2.f; g2= 0.f; g3=1.f; }
  else if (l == 2) { g0=-1.f; g1= 0.f; g2=-2.f; g3=1.f; }
  else             { g0= 0.f; g1= 1.f; g2= 1.f; g3=4.f; }
  v2f czv[4];
  { float sz, cz;
    hsc(theta*g0, &sz, &cz); czv[0].x = cz; czv[0].y = sz;
    hsc(theta*g1, &sz, &cz); czv[1].x = cz; czv[1].y = sz;
    hsc(theta*g2, &sz, &cz); czv[2].x = cz; czv[2].y = sz;
    hsc(theta*g3, &sz, &cz); czv[3].x = cz; czv[3].y = sz; }

  // state: amp n = 4*l + k; s[k] = (re, im) packed
  v2f s[4];
#pragma unroll
  for (int k = 0; k < 4; ++k) { s[k].x = 0.f; s[k].y = 0.f; }
  if (l0) s[0].x = 1.f;

  v2f h1v[5];
#pragma unroll
  for (int j = 0; j < 5; ++j) { h1v[j].x = 0.f; h1v[j].y = 0.f; }
  const float* swl = sw + 5 * l * 784;

  float a0, a1, a2, a3, a4;
  v2f WcA, WcB, WnA, WnB;
  v2f npA, npB;
  v2f pdA, pdB;                                  // pending readout (0-seeded)
  pdA.x = 0.f; pdA.y = 0.f; pdB.x = 0.f; pdB.y = 0.f;
  int pdWin = 0;

  // ================= main rows: wi = 0..12 (h = 4 always) =================
#pragma unroll 1
  for (int wi = 0; wi < 13; ++wi) {
    const float* rp = img + (2 * wi) * 28;
    const float* pA = rp + offA;
    const float* pB = rp + offB;

    // peel wj = 0: direct load + build only (prev row's pending carries over)
    {
      v4f Ac = loadu4(pA);
      v4f Bc = loadu4(pB);
      SEL_MAIN;
      build_gate(a0, a1, a2, a3, a4, WcA, WcB);
    }

    // prefetch window 1
    v4f An = loadu4(pA + 2);
    v4f Bn = loadu4(pB + 2);

    // hot loop: wj = 1..12 — branch-free; unroll 6 (12 divides evenly;
    // wider scheduling window, body ~12KB < L1I).
    // Body: BF_LOAD(wj-2) || build(wj) || apply(wj-1) || BF_USE(wj-2).
#pragma unroll 6
    for (int wj = 1; wj <= 12; ++wj) {
      BF_LOAD;                                    // LDS reads, consumed at bottom
      v4f Ac = An, Bc = Bn;
      const int jn = (wj < 12) ? 2 * (wj + 1) : 24;   // clamped dummy on last iter
      An = loadu4(pA + jn);
      Bn = loadu4(pB + jn);
      SEL_MAIN;
      build_gate(a0, a1, a2, a3, a4, WnA, WnB);
      APPLY_Z;                                   // window wj-1 -> np
      BF_USE;                                    // window wj-2 (or older)
      SHIFT_PEND(wi * 14 + wj - 1);
      ROTATE_W;
    }

    // peel wj = 13: w=2 window (cols 26,27)
    {
      v2f C0 = *(const v2f*)(rp + (l1 ? 56 : 0)  + 26);
      v2f C1 = *(const v2f*)(rp + (l1 ? 84 : 28) + 26);
      v2f C2 = *(const v2f*)(rp + (l1 ? 84 : 56) + 26);
      a0 = l0 ? C0.x : (l1 ? C0.y : 0.f);
      a1 = l0 ? C0.y : (l1 ? C1.x : 0.f);
      a2 = l0 ? C1.x : (l1 ? C1.y : 0.f);
      a3 = l0 ? C1.y : 0.f;
      a4 = l0 ? C2.x : 0.f;
      build_gate(a0, a1, a2, a3, a4, WnA, WnB);
    }
    APPLY_Z;                                     // window 12
    BF_FOLD;                                     // window 11
    SHIFT_PEND(wi * 14 + 12);
    ROTATE_W;
    APPLY_Z;                                     // window 13
    BF_FOLD;                                     // window 12
    SHIFT_PEND(wi * 14 + 13);
  }

  // ================= tail row: wi = 13 (h = 2, i = 26) =================
  {
    const float* pA = img + 728 + (l1 ? 28 : 0);  // row 26 (+1 for l1)
    const float* pB = img + 756;                  // row 27

    // peel wj = 0
    {
      v4f Ac = loadu4(pA);
      v4f Bc = loadu4(pB);
      SEL_TAIL;
      build_gate(a0, a1, a2, a3, a4, WcA, WcB);
    }

    v4f An = loadu4(pA + 2);
    v4f Bn = loadu4(pB + 2);

#pragma unroll 6
    for (int wj = 1; wj <= 12; ++wj) {
      BF_LOAD;
      v4f Ac = An, Bc = Bn;
      const int jn = (wj < 12) ? 2 * (wj + 1) : 24;
      An = loadu4(pA + jn);
      Bn = loadu4(pB + jn);
      SEL_TAIL;
      build_gate(a0, a1, a2, a3, a4, WnA, WnB);
      APPLY_Z;
      BF_USE;
      SHIFT_PEND(182 + wj - 1);
      ROTATE_W;
    }

    // peel wj = 13: 2x2 window (rows 26,27 cols 26,27), l0 only
    {
      v2f D0 = *(const v2f*)(img + 26 * 28 + 26);
      v2f D1 = *(const v2f*)(img + 27 * 28 + 26);
      a0 = l0 ? D0.x : 0.f;
      a1 = l0 ? D0.y : 0.f;
      a2 = l0 ? D1.x : 0.f;
      a3 = l0 ? D1.y : 0.f;
      a4 = 0.f;
      build_gate(a0, a1, a2, a3, a4, WnA, WnB);
    }
    APPLY_Z;                                     // window 194
    BF_FOLD;                                     // window 193
    SHIFT_PEND(182 + 12);
    ROTATE_W;
    APPLY_Z;                                     // window 195
    BF_FOLD;                                     // window 194
    SHIFT_PEND(182 + 13);
  }

  // drain the pipeline: fold window 195
  BF_FOLD;

  // ---- epilogue: bias + leaky relu + fc2, reduce over group ----
  float pa = 0.f, pb = 0.f;
#pragma unroll
  for (int j = 0; j < 5; ++j) {
    const int r = 5 * l + j;
    float v = h1v[j].x + h1v[j].y + fc1_b[r];
    v = (v > 0.f) ? v : 0.1f * v;
    pa = fmaf(fc2_w[r],      v, pa);
    pb = fmaf(fc2_w[20 + r], v, pb);
  }
  pa += dppf<QP_XOR1>(pa); pa += dppf<QP_XOR2>(pa);
  pb += dppf<QP_XOR1>(pb); pb += dppf<QP_XOR2>(pb);
  if (l0) {
    float2 res; res.x = pa + fc2_b[0]; res.y = pb + fc2_b[1];
    *(float2*)(out + (size_t)b * 2) = res;
  }
}

extern "C" void kernel_launch(void* const* d_in, const int* in_sizes, int n_in,
                              void* d_out, int out_size, void* d_ws, size_t ws_size,
                              hipStream_t stream) {
  const float* x      = (const float*)d_in[0];
  const float* crz_t  = (const float*)d_in[1];
  const float* ry_t   = (const float*)d_in[2];
  const float* fc1_w  = (const float*)d_in[3];
  const float* fc1_b  = (const float*)d_in[4];
  const float* fc2_w  = (const float*)d_in[5];
  const float* fc2_b  = (const float*)d_in[6];
  float* out = (float*)d_out;
  const int B = in_sizes[0] / 784;
  const int grid = (B * 4 + 255) / 256;
  quanv_kernel<<<grid, 256, 0, stream>>>(x, crz_t, ry_t, fc1_w, fc1_b,
                                         fc2_w, fc2_b, out, B);
}

// Round 11
// 203.972 us; speedup vs baseline: 1.1087x; 1.1087x over previous
//
#include <hip/hip_runtime.h>

#define RS2f 0.70710678118654752f

// DPP quad_perm encodings: sel0 | sel1<<2 | sel2<<4 | sel3<<6
#define QP_XOR1 0xB1   // [1,0,3,2]
#define QP_XOR2 0x4E   // [2,3,0,1]
#define QP_BC0  0x00
#define QP_BC1  0x55
#define QP_BC2  0xAA
#define QP_BC3  0xFF

typedef float v2f __attribute__((ext_vector_type(2)));
typedef float v4f __attribute__((ext_vector_type(4)));
typedef v4f v4fu __attribute__((aligned(4)));   // 4B-aligned vector load

template<int CTRL> __device__ __forceinline__ float dppf(float x) {
  return __int_as_float(__builtin_amdgcn_update_dpp(
      0, __float_as_int(x), CTRL, 0xF, 0xF, true));
}
template<int CTRL> __device__ __forceinline__ v2f dpp2(v2f v) {
  v2f r; r.x = dppf<CTRL>(v.x); r.y = dppf<CTRL>(v.y); return r;
}

__device__ __forceinline__ float sxor(float x, int sm) {
  return __int_as_float(__float_as_int(x) ^ sm);
}
__device__ __forceinline__ v2f vlo(v4f v) { return __builtin_shufflevector(v, v, 0, 1); }
__device__ __forceinline__ v2f vhi(v4f v) { return __builtin_shufflevector(v, v, 2, 3); }
__device__ __forceinline__ v4f loadu4(const float* p) { return *(const v4fu*)p; }

// ---- packed-fp32 helpers: complex / packed arithmetic in single VOP3P ops --
// perp(x) = (-x.y, x.x) = i*x ; perc(x) = (x.y, -x.x) = -i*x

// plain packed: d = a*b + c
__device__ __forceinline__ v2f pk_fma2(v2f a, v2f b, v2f c) {
  v2f d;
  asm("v_pk_fma_f32 %0, %1, %2, %3 op_sel:[0,0,0] op_sel_hi:[1,1,1]"
      : "=v"(d) : "v"(a), "v"(b), "v"(c));
  return d;
}
// plain packed: d = a*b
__device__ __forceinline__ v2f pk_mul2(v2f a, v2f b) {
  v2f d;
  asm("v_pk_mul_f32 %0, %1, %2 op_sel:[0,0] op_sel_hi:[1,1]"
      : "=v"(d) : "v"(a), "v"(b));
  return d;
}
// plain packed: d = a + b
__device__ __forceinline__ v2f pk_add2(v2f a, v2f b) {
  v2f d;
  asm("v_pk_add_f32 %0, %1, %2 op_sel:[0,0] op_sel_hi:[1,1]"
      : "=v"(d) : "v"(a), "v"(b));
  return d;
}
// d = c.lo * x + acc
__device__ __forceinline__ v2f pk_fma_rlo(v2f c, v2f x, v2f acc) {
  v2f d;
  asm("v_pk_fma_f32 %0, %1, %2, %3 op_sel:[0,0,0] op_sel_hi:[0,1,1]"
      : "=v"(d) : "v"(c), "v"(x), "v"(acc));
  return d;
}
// d = -c.lo * x + acc
__device__ __forceinline__ v2f pk_fma_nrlo(v2f c, v2f x, v2f acc) {
  v2f d;
  asm("v_pk_fma_f32 %0, %1, %2, %3 op_sel:[0,0,0] op_sel_hi:[0,1,1] neg_lo:[1,0,0] neg_hi:[1,0,0]"
      : "=v"(d) : "v"(c), "v"(x), "v"(acc));
  return d;
}
// d = c.hi * x + acc
__device__ __forceinline__ v2f pk_fma_rhi(v2f c, v2f x, v2f acc) {
  v2f d;
  asm("v_pk_fma_f32 %0, %1, %2, %3 op_sel:[1,0,0] op_sel_hi:[1,1,1]"
      : "=v"(d) : "v"(c), "v"(x), "v"(acc));
  return d;
}
// d = -c.hi * x + acc
__device__ __forceinline__ v2f pk_fma_nrhi(v2f c, v2f x, v2f acc) {
  v2f d;
  asm("v_pk_fma_f32 %0, %1, %2, %3 op_sel:[1,0,0] op_sel_hi:[1,1,1] neg_lo:[1,0,0] neg_hi:[1,0,0]"
      : "=v"(d) : "v"(c), "v"(x), "v"(acc));
  return d;
}
// d = c.hi * perp(x) + acc
__device__ __forceinline__ v2f pk_fma_rhip(v2f c, v2f x, v2f acc) {
  v2f d;
  asm("v_pk_fma_f32 %0, %1, %2, %3 op_sel:[1,1,0] op_sel_hi:[1,0,1] neg_lo:[0,1,0]"
      : "=v"(d) : "v"(c), "v"(x), "v"(acc));
  return d;
}
// d = c.hi * perc(x) + acc
__device__ __forceinline__ v2f pk_fma_rhic(v2f c, v2f x, v2f acc) {
  v2f d;
  asm("v_pk_fma_f32 %0, %1, %2, %3 op_sel:[1,1,0] op_sel_hi:[1,0,1] neg_hi:[0,1,0]"
      : "=v"(d) : "v"(c), "v"(x), "v"(acc));
  return d;
}
// d = c.hi * perp(x)
__device__ __forceinline__ v2f pk_mul_rhip(v2f c, v2f x) {
  v2f d;
  asm("v_pk_mul_f32 %0, %1, %2 op_sel:[1,1] op_sel_hi:[1,0] neg_lo:[0,1]"
      : "=v"(d) : "v"(c), "v"(x));
  return d;
}
// d = c.hi * x
__device__ __forceinline__ v2f pk_mul_rhi(v2f c, v2f x) {
  v2f d;
  asm("v_pk_mul_f32 %0, %1, %2 op_sel:[1,0] op_sel_hi:[1,1]"
      : "=v"(d) : "v"(c), "v"(x));
  return d;
}
// d = -c.hi * x
__device__ __forceinline__ v2f pk_mul_nrhi(v2f c, v2f x) {
  v2f d;
  asm("v_pk_mul_f32 %0, %1, %2 op_sel:[1,0] op_sel_hi:[1,1] neg_lo:[1,0] neg_hi:[1,0]"
      : "=v"(d) : "v"(c), "v"(x));
  return d;
}
// d = c.lo * x
__device__ __forceinline__ v2f pk_mul_rlo(v2f c, v2f x) {
  v2f d;
  asm("v_pk_mul_f32 %0, %1, %2 op_sel:[0,0] op_sel_hi:[0,1]"
      : "=v"(d) : "v"(c), "v"(x));
  return d;
}

// native half-angle sincos: s = sin(x/2), c = cos(x/2)
__device__ __forceinline__ void hsc(float x, float* s, float* c) {
  float t = x * 0.07957747154594767f;   // 0.5 / (2*pi), input in revolutions
  *s = __builtin_amdgcn_sinf(t);
  *c = __builtin_amdgcn_cosf(t);
}

// Closed-form row0 of U = RZ(a4)RY(a3)RZ(a2)RY(a1)RZ(a0)·H  (verified r8).
__device__ __forceinline__ void build_gate(float a0, float a1, float a2, float a3, float a4,
                                           v2f &WA, v2f &WB) {
  float sBp, cBp, sBm, cBm, sC, cC, sP, cP, sM, cM;
  hsc(a1 + a3, &sBp, &cBp);
  hsc(a1 - a3, &sBm, &cBm);
  hsc(a2,      &sC,  &cC);
  hsc(a0 + a4, &sP,  &cP);
  hsc(a0 - a4, &sM,  &cM);
  float m00r =  cBp * cC, m00i = -cBm * sC;
  float m01r = -sBp * cC, m01i =  sBm * sC;
  float alr = fmaf(m00r, cP,  m00i * sP);
  float ali = fmaf(m00i, cP, -m00r * sP);
  float ber = fmaf(m01r, cM, -m01i * sM);
  float bei = fmaf(m01i, cM,  m01r * sM);
  WA.x = RS2f * (alr + ber); WA.y = RS2f * (ali + bei);
  WB.x = RS2f * (alr - ber); WB.y = RS2f * (ali - bei);
}

// ---- per-lane direct angle selects (verified r4) ----
#define SEL_MAIN                                                             \
  a0 = l3 ? Ac.w : Ac.x;                                                     \
  a1 = l3 ? 0.f  : Ac.y;                                                     \
  a2 = l2 ? Bc.x : (l3 ? 0.f : Ac.z);                                        \
  a3 = l0 ? Ac.w : (l1 ? Bc.x : (l2 ? Bc.y : 0.f));                          \
  a4 = l0 ? Bc.x : (l1 ? Bc.y : (l2 ? Bc.z : 0.f));

#define SEL_TAIL                                                             \
  a0 = l0 ? Ac.x : (l1 ? Ac.y : 0.f);                                        \
  a1 = l0 ? Ac.y : (l1 ? Ac.z : 0.f);                                        \
  a2 = l0 ? Ac.z : (l1 ? Ac.w : 0.f);                                        \
  a3 = l0 ? Ac.w : 0.f;                                                      \
  a4 = l0 ? Bc.x : 0.f;

// Apply gate (WcA/WcB packed pairs) + CRZ + Ry + Z expectations.
// Same math as r3/r4 (verified); intra-lane Ry pair merged into one
// 4x4 real matrix pass (Ry(bit1)⊗Ry(bit0), constants C2CS/S2CS).
#define APPLY_Z do {                                                         \
  { v2f UA = dpp2<QP_BC0>(WcA), UB = dpp2<QP_BC0>(WcB);                      \
    UA.x = sxor(UA.x, sm0); UB.y = sxor(UB.y, sm0);                          \
    _Pragma("unroll")                                                        \
    for (int k = 0; k < 4; ++k) {                                            \
      v2f p = dpp2<QP_XOR2>(s[k]);                                           \
      v2f a = s[k];                                                          \
      s[k] = pk_fma_rlo(UA, a, pk_fma_rhip(UA, a,                            \
               pk_fma_rlo(UB, p, pk_mul_rhip(UB, p))));                      \
    } }                                                                      \
  { v2f UA = dpp2<QP_BC1>(WcA), UB = dpp2<QP_BC1>(WcB);                      \
    UA.x = sxor(UA.x, sm1); UB.y = sxor(UB.y, sm1);                          \
    _Pragma("unroll")                                                        \
    for (int k = 0; k < 4; ++k) {                                            \
      v2f p = dpp2<QP_XOR1>(s[k]);                                           \
      v2f a = s[k];                                                          \
      s[k] = pk_fma_rlo(UA, a, pk_fma_rhip(UA, a,                            \
               pk_fma_rlo(UB, p, pk_mul_rhip(UB, p))));                      \
    } }                                                                      \
  { v2f W0 = dpp2<QP_BC2>(WcA), W1 = dpp2<QP_BC2>(WcB);                      \
    _Pragma("unroll")                                                        \
    for (int k = 0; k < 2; ++k) {                                            \
      v2f lo = s[k], hi = s[k+2];                                            \
      s[k]   = pk_fma_rlo(W0, lo, pk_fma_rhip(W0, lo,                        \
                 pk_fma_rlo(W1, hi, pk_mul_rhip(W1, hi))));                  \
      s[k+2] = pk_fma_rlo(W1, lo, pk_fma_rhic(W1, lo,                        \
                 pk_fma_nrlo(W0, hi, pk_mul_rhip(W0, hi))));                 \
    } }                                                                      \
  { v2f W0 = dpp2<QP_BC3>(WcA), W1 = dpp2<QP_BC3>(WcB);                      \
    _Pragma("unroll")                                                        \
    for (int k = 0; k < 4; k += 2) {                                         \
      v2f lo = s[k], hi = s[k+1];                                            \
      s[k]   = pk_fma_rlo(W0, lo, pk_fma_rhip(W0, lo,                        \
                 pk_fma_rlo(W1, hi, pk_mul_rhip(W1, hi))));                  \
      s[k+1] = pk_fma_rlo(W1, lo, pk_fma_rhic(W1, lo,                        \
                 pk_fma_nrlo(W0, hi, pk_mul_rhip(W0, hi))));                 \
    } }                                                                      \
  _Pragma("unroll")                                                          \
  for (int k = 0; k < 4; ++k)                                                \
    s[k] = pk_fma_rlo(czv[k], s[k], pk_mul_rhip(czv[k], s[k]));              \
  _Pragma("unroll")                                                          \
  for (int k = 0; k < 4; ++k) {                                              \
    v2f p = dpp2<QP_XOR2>(s[k]);                                             \
    s[k] = pk_fma_rlo(RY0, s[k], pk_mul_rhi(RY0, p));                        \
  }                                                                          \
  _Pragma("unroll")                                                          \
  for (int k = 0; k < 4; ++k) {                                              \
    v2f p = dpp2<QP_XOR1>(s[k]);                                             \
    s[k] = pk_fma_rlo(RY1, s[k], pk_mul_rhi(RY1, p));                        \
  }                                                                          \
  { /* merged intra-lane Ry⊗Ry (stride-2 stage then stride-1 stage):      */ \
    /* row0: c²t0 -cs t1 -cs t2 +s²t3 ; row1: cs t0 +c²t1 -s²t2 -cs t3    */ \
    /* row2: cs t0 -s²t1 +c²t2 -cs t3 ; row3: s²t0 +cs t1 +cs t2 +c²t3    */ \
    v2f t0 = s[0], t1 = s[1], t2 = s[2], t3 = s[3];                          \
    s[0] = pk_fma_rlo(C2CS, t0, pk_fma_nrhi(C2CS, t1,                        \
             pk_fma_nrhi(C2CS, t2, pk_mul_rlo(S2CS, t3))));                  \
    s[1] = pk_fma_rhi(C2CS, t0, pk_fma_rlo(C2CS, t1,                         \
             pk_fma_nrlo(S2CS, t2, pk_mul_nrhi(C2CS, t3))));                 \
    s[2] = pk_fma_rhi(C2CS, t0, pk_fma_nrlo(S2CS, t1,                        \
             pk_fma_rlo(C2CS, t2, pk_mul_nrhi(C2CS, t3))));                  \
    s[3] = pk_fma_rlo(S2CS, t0, pk_fma_rhi(C2CS, t1,                         \
             pk_fma_rhi(C2CS, t2, pk_mul_rlo(C2CS, t3))));                   \
  }                                                                          \
  { v2f q0 = pk_mul2(s[0], s[0]), q1 = pk_mul2(s[1], s[1]);                  \
    v2f q2 = pk_mul2(s[2], s[2]), q3 = pk_mul2(s[3], s[3]);                  \
    float p0 = q0.x + q0.y, p1 = q1.x + q1.y;                                \
    float p2 = q2.x + q2.y, p3 = q3.x + q3.y;                                \
    float s01 = p0 + p1, s23 = p2 + p3;                                      \
    float t_  = s01 + s23;                                                   \
    npA.x = sxor(t_, sm0);                                                   \
    npA.y = sxor(t_, sm1);                                                   \
    npB.x = s01 - s23;                                                       \
    npB.y = (p0 - p1) + (p2 - p3);                                           \
  }                                                                          \
} while (0)

// LDS weight reads for the PENDING window — issued early (top of body).
#define BF_LOAD                                                              \
  const float* wp = swl + pdWin * 4;                                         \
  v4f wv0 = *(const v4f*)(wp);                                               \
  v4f wv1 = *(const v4f*)(wp + 784);                                         \
  v4f wv2 = *(const v4f*)(wp + 1568);                                        \
  v4f wv3 = *(const v4f*)(wp + 2352);                                        \
  v4f wv4 = *(const v4f*)(wp + 3136);

// Packed butterfly + packed fc1 fold — all through explicit pk asm.
#define BF_USE do {                                                          \
  v2f oA = pdA, oB = pdB;                                                    \
  oA = pk_add2(oA, dpp2<QP_XOR1>(oA)); oA = pk_add2(oA, dpp2<QP_XOR2>(oA));  \
  oB = pk_add2(oB, dpp2<QP_XOR1>(oB)); oB = pk_add2(oB, dpp2<QP_XOR2>(oB));  \
  h1v[0] = pk_fma2(vlo(wv0), oA, pk_fma2(vhi(wv0), oB, h1v[0]));             \
  h1v[1] = pk_fma2(vlo(wv1), oA, pk_fma2(vhi(wv1), oB, h1v[1]));             \
  h1v[2] = pk_fma2(vlo(wv2), oA, pk_fma2(vhi(wv2), oB, h1v[2]));             \
  h1v[3] = pk_fma2(vlo(wv3), oA, pk_fma2(vhi(wv3), oB, h1v[3]));             \
  h1v[4] = pk_fma2(vlo(wv4), oA, pk_fma2(vhi(wv4), oB, h1v[4]));             \
} while (0)

#define BF_FOLD do { BF_LOAD; BF_USE; } while (0)

#define SHIFT_PEND(WIN)  pdA = npA; pdB = npB; pdWin = (WIN);
#define ROTATE_W  WcA = WnA; WcB = WnB;

__global__ void __launch_bounds__(256)
quanv_kernel(const float* __restrict__ x,
             const float* __restrict__ crz_t,
             const float* __restrict__ ry_t,
             const float* __restrict__ fc1_w,
             const float* __restrict__ fc1_b,
             const float* __restrict__ fc2_w,
             const float* __restrict__ fc2_b,
             float* __restrict__ out, int B)
{
  __shared__ float sw[20 * 784];
  const int tid = threadIdx.x;
  for (int i = tid; i < (20 * 784) / 4; i += 256)
    ((float4*)sw)[i] = ((const float4*)fc1_w)[i];
  __syncthreads();

  const int l = tid & 3;                       // lane within 4-lane group
  const int b = (blockIdx.x * 256 + tid) >> 2; // element id
  if (b >= B) return;
  const float* img = x + (size_t)b * 784;
  const bool l0 = (l == 0), l1 = (l == 1), l2 = (l == 2), l3 = (l == 3);

  // per-lane load offsets (floats) for the direct-select scheme
  const int offA = l3 ? 84 : l * 29;                 // row i+l, col +l (l3: row i+3, col +0)
  const int offB = (l >= 2) ? 84 : (l + 1) * 28;     // row i+min(l+1,3), col +0

  // ---- uniform scalar-derived constants ----
  const float theta = crz_t[0];
  const float ryt   = ry_t[0];
  float cry, sry;
  hsc(ryt, &sry, &cry);
  const float sgn0 = (l & 2) ? sry : -sry;
  const float sgn1 = (l & 1) ? sry : -sry;
  const int sm0 = (l & 2) ? (int)0x80000000 : 0;
  const int sm1 = (l & 1) ? (int)0x80000000 : 0;

  v2f RY0, RY1, C2CS, S2CS;
  RY0.x = cry; RY0.y = sgn0;
  RY1.x = cry; RY1.y = sgn1;
  C2CS.x = cry * cry; C2CS.y = cry * sry;   // (c^2, c*s)
  S2CS.x = sry * sry; S2CS.y = cry * sry;   // (s^2, c*s)

  float g0,g1,g2,g3;
  if      (l == 0) { g0= 0.f; g1=-1.f; g2=-1.f; g3=0.f; }
  else if (l == 1) { g0=-1.f; g1=-2.f; g2= 0.f; g3=1.f; }
  else if (l == 2) { g0=-1.f; g1= 0.f; g2=-2.f; g3=1.f; }
  else             { g0= 0.f; g1= 1.f; g2= 1.f; g3=4.f; }
  v2f czv[4];
  { float sz, cz;
    hsc(theta*g0, &sz, &cz); czv[0].x = cz; czv[0].y = sz;
    hsc(theta*g1, &sz, &cz); czv[1].x = cz; czv[1].y = sz;
    hsc(theta*g2, &sz, &cz); czv[2].x = cz; czv[2].y = sz;
    hsc(theta*g3, &sz, &cz); czv[3].x = cz; czv[3].y = sz; }

  // state: amp n = 4*l + k; s[k] = (re, im) packed
  v2f s[4];
#pragma unroll
  for (int k = 0; k < 4; ++k) { s[k].x = 0.f; s[k].y = 0.f; }
  if (l0) s[0].x = 1.f;

  v2f h1v[5];
#pragma unroll
  for (int j = 0; j < 5; ++j) { h1v[j].x = 0.f; h1v[j].y = 0.f; }
  const float* swl = sw + 5 * l * 784;

  float a0, a1, a2, a3, a4;
  v2f WcA, WcB, WnA, WnB;
  v2f npA, npB;
  v2f pdA, pdB;                                  // pending readout (0-seeded)
  pdA.x = 0.f; pdA.y = 0.f; pdB.x = 0.f; pdB.y = 0.f;
  int pdWin = 0;

  // ================= main rows: wi = 0..12 (h = 4 always) =================
#pragma unroll 1
  for (int wi = 0; wi < 13; ++wi) {
    const float* rp = img + (2 * wi) * 28;
    const float* pA = rp + offA;
    const float* pB = rp + offB;

    // peel wj = 0: direct load + build only (prev row's pending carries over)
    {
      v4f Ac = loadu4(pA);
      v4f Bc = loadu4(pB);
      SEL_MAIN;
      build_gate(a0, a1, a2, a3, a4, WcA, WcB);
    }

    // prefetch window 1
    v4f An = loadu4(pA + 2);
    v4f Bn = loadu4(pB + 2);

    // hot loop: wj = 1..12 — branch-free; unroll 4 (measured optimum:
    // unroll 2 = 146.8, unroll 4 = 143.2, unroll 6 = 162.3 µs).
    // Body: BF_LOAD(wj-2) || build(wj) || apply(wj-1) || BF_USE(wj-2).
#pragma unroll 4
    for (int wj = 1; wj <= 12; ++wj) {
      BF_LOAD;                                    // LDS reads, consumed at bottom
      v4f Ac = An, Bc = Bn;
      const int jn = (wj < 12) ? 2 * (wj + 1) : 24;   // clamped dummy on last iter
      An = loadu4(pA + jn);
      Bn = loadu4(pB + jn);
      SEL_MAIN;
      build_gate(a0, a1, a2, a3, a4, WnA, WnB);
      APPLY_Z;                                   // window wj-1 -> np
      BF_USE;                                    // window wj-2 (or older)
      SHIFT_PEND(wi * 14 + wj - 1);
      ROTATE_W;
    }

    // peel wj = 13: w=2 window (cols 26,27)
    {
      v2f C0 = *(const v2f*)(rp + (l1 ? 56 : 0)  + 26);
      v2f C1 = *(const v2f*)(rp + (l1 ? 84 : 28) + 26);
      v2f C2 = *(const v2f*)(rp + (l1 ? 84 : 56) + 26);
      a0 = l0 ? C0.x : (l1 ? C0.y : 0.f);
      a1 = l0 ? C0.y : (l1 ? C1.x : 0.f);
      a2 = l0 ? C1.x : (l1 ? C1.y : 0.f);
      a3 = l0 ? C1.y : 0.f;
      a4 = l0 ? C2.x : 0.f;
      build_gate(a0, a1, a2, a3, a4, WnA, WnB);
    }
    APPLY_Z;                                     // window 12
    BF_FOLD;                                     // window 11
    SHIFT_PEND(wi * 14 + 12);
    ROTATE_W;
    APPLY_Z;                                     // window 13
    BF_FOLD;                                     // window 12
    SHIFT_PEND(wi * 14 + 13);
  }

  // ================= tail row: wi = 13 (h = 2, i = 26) =================
  {
    const float* pA = img + 728 + (l1 ? 28 : 0);  // row 26 (+1 for l1)
    const float* pB = img + 756;                  // row 27

    // peel wj = 0
    {
      v4f Ac = loadu4(pA);
      v4f Bc = loadu4(pB);
      SEL_TAIL;
      build_gate(a0, a1, a2, a3, a4, WcA, WcB);
    }

    v4f An = loadu4(pA + 2);
    v4f Bn = loadu4(pB + 2);

#pragma unroll 4
    for (int wj = 1; wj <= 12; ++wj) {
      BF_LOAD;
      v4f Ac = An, Bc = Bn;
      const int jn = (wj < 12) ? 2 * (wj + 1) : 24;
      An = loadu4(pA + jn);
      Bn = loadu4(pB + jn);
      SEL_TAIL;
      build_gate(a0, a1, a2, a3, a4, WnA, WnB);
      APPLY_Z;
      BF_USE;
      SHIFT_PEND(182 + wj - 1);
      ROTATE_W;
    }

    // peel wj = 13: 2x2 window (rows 26,27 cols 26,27), l0 only
    {
      v2f D0 = *(const v2f*)(img + 26 * 28 + 26);
      v2f D1 = *(const v2f*)(img + 27 * 28 + 26);
      a0 = l0 ? D0.x : 0.f;
      a1 = l0 ? D0.y : 0.f;
      a2 = l0 ? D1.x : 0.f;
      a3 = l0 ? D1.y : 0.f;
      a4 = 0.f;
      build_gate(a0, a1, a2, a3, a4, WnA, WnB);
    }
    APPLY_Z;                                     // window 194
    BF_FOLD;                                     // window 193
    SHIFT_PEND(182 + 12);
    ROTATE_W;
    APPLY_Z;                                     // window 195
    BF_FOLD;                                     // window 194
    SHIFT_PEND(182 + 13);
  }

  // drain the pipeline: fold window 195
  BF_FOLD;

  // ---- epilogue: bias + leaky relu + fc2, reduce over group ----
  float pa = 0.f, pb = 0.f;
#pragma unroll
  for (int j = 0; j < 5; ++j) {
    const int r = 5 * l + j;
    float v = h1v[j].x + h1v[j].y + fc1_b[r];
    v = (v > 0.f) ? v : 0.1f * v;
    pa = fmaf(fc2_w[r],      v, pa);
    pb = fmaf(fc2_w[20 + r], v, pb);
  }
  pa += dppf<QP_XOR1>(pa); pa += dppf<QP_XOR2>(pa);
  pb += dppf<QP_XOR1>(pb); pb += dppf<QP_XOR2>(pb);
  if (l0) {
    float2 res; res.x = pa + fc2_b[0]; res.y = pb + fc2_b[1];
    *(float2*)(out + (size_t)b * 2) = res;
  }
}

extern "C" void kernel_launch(void* const* d_in, const int* in_sizes, int n_in,
                              void* d_out, int out_size, void* d_ws, size_t ws_size,
                              hipStream_t stream) {
  const float* x      = (const float*)d_in[0];
  const float* crz_t  = (const float*)d_in[1];
  const float* ry_t   = (const float*)d_in[2];
  const float* fc1_w  = (const float*)d_in[3];
  const float* fc1_b  = (const float*)d_in[4];
  const float* fc2_w  = (const float*)d_in[5];
  const float* fc2_b  = (const float*)d_in[6];
  float* out = (float*)d_out;
  const int B = in_sizes[0] / 784;
  const int grid = (B * 4 + 255) / 256;
  quanv_kernel<<<grid, 256, 0, stream>>>(x, crz_t, ry_t, fc1_w, fc1_b,
                                         fc2_w, fc2_b, out, B);
}